// Round 1
// baseline (2832.385 us; speedup 1.0000x reference)
//
#include <hip/hip_runtime.h>

// ---------------------------------------------------------------------------
// VGAE encoder: 4x GCNConv (last two fused to 64 channels).
//   deg/dis -> [gemm(+selfloop init) -> edge scatter] x3 -> bias epilogue
// ---------------------------------------------------------------------------

#define TB 256

// deg accumulation over dst (self-loop +1 folded into k_dis)
__global__ void k_deg(const int* __restrict__ dst, int E, float* __restrict__ deg) {
    int e = blockIdx.x * blockDim.x + threadIdx.x;
    if (e < E) atomicAdd(&deg[dst[e]], 1.0f);
}

__global__ void k_dis(float* __restrict__ deg, int n) {
    int i = blockIdx.x * blockDim.x + threadIdx.x;
    if (i < n) deg[i] = rsqrtf(deg[i] + 1.0f);   // +1 = self loop
}

// h = pre(in) @ W ;  acc = dis^2 * h   (self-loop contribution)
// pre(v) = bin ? relu(v + bin[c]) : v
// block: 256 threads = 8 nodes x 32 channels
__global__ void k_gemm32(const float* __restrict__ in, const float* __restrict__ W,
                         const float* __restrict__ bin, const float* __restrict__ dis,
                         float* __restrict__ h, float* __restrict__ acc, int n) {
    __shared__ float Ws[32][32];
    __shared__ float Xs[8][33];
    int t = threadIdx.x;
    for (int i = t; i < 1024; i += 256) Ws[i >> 5][i & 31] = W[i];
    int node0 = blockIdx.x * 8;
    {
        int r = t >> 5, c = t & 31;
        int node = node0 + r;
        float v = 0.f;
        if (node < n) {
            v = in[node * 32 + c];
            if (bin) v = fmaxf(v + bin[c], 0.f);
        }
        Xs[r][c] = v;
    }
    __syncthreads();
    int r = t >> 5, c = t & 31;
    int node = node0 + r;
    if (node >= n) return;
    float sum = 0.f;
#pragma unroll
    for (int k = 0; k < 32; ++k) sum += Xs[r][k] * Ws[k][c];
    h[node * 32 + c] = sum;
    float d = dis[node];
    acc[node * 32 + c] = d * d * sum;
}

// fused mu/logvar: h64 = relu(in + bin) @ [Wmu | Wlv];  acc64 = dis^2 * h64
// block: 256 threads = 4 nodes x 64 channels
__global__ void k_gemm64(const float* __restrict__ in, const float* __restrict__ Wmu,
                         const float* __restrict__ Wlv, const float* __restrict__ bin,
                         const float* __restrict__ dis,
                         float* __restrict__ h, float* __restrict__ acc, int n) {
    __shared__ float Ws[32][64];
    __shared__ float Xs[4][33];
    int t = threadIdx.x;
    for (int i = t; i < 1024; i += 256) {
        int k = i >> 5, c = i & 31;
        Ws[k][c]      = Wmu[i];
        Ws[k][c + 32] = Wlv[i];
    }
    if (t < 128) {
        int r = t >> 5, c = t & 31;
        int node = blockIdx.x * 4 + r;
        float v = 0.f;
        if (node < n) v = fmaxf(in[node * 32 + c] + bin[c], 0.f);
        Xs[r][c] = v;
    }
    __syncthreads();
    int r = t >> 6, c = t & 63;
    int node = blockIdx.x * 4 + r;
    if (node >= n) return;
    float sum = 0.f;
#pragma unroll
    for (int k = 0; k < 32; ++k) sum += Xs[r][k] * Ws[k][c];
    h[node * 64 + c] = sum;
    float d = dis[node];
    acc[node * 64 + c] = d * d * sum;
}

// edge scatter, 32 channels: 8 threads/edge, float4 gather + 4 scalar atomics
__global__ void k_scatter32(const int* __restrict__ src, const int* __restrict__ dst,
                            const float* __restrict__ dis, const float* __restrict__ h,
                            float* __restrict__ acc, int E) {
    int t = blockIdx.x * blockDim.x + threadIdx.x;
    int e = t >> 3;
    if (e >= E) return;
    int c4 = (t & 7) * 4;
    int s = src[e], d = dst[e];
    float norm = dis[s] * dis[d];
    float4 hv = *(const float4*)(h + (size_t)s * 32 + c4);
    float* out = acc + (size_t)d * 32 + c4;
    atomicAdd(out + 0, norm * hv.x);
    atomicAdd(out + 1, norm * hv.y);
    atomicAdd(out + 2, norm * hv.z);
    atomicAdd(out + 3, norm * hv.w);
}

// edge scatter, 64 channels: 16 threads/edge
__global__ void k_scatter64(const int* __restrict__ src, const int* __restrict__ dst,
                            const float* __restrict__ dis, const float* __restrict__ h,
                            float* __restrict__ acc, int E) {
    int t = blockIdx.x * blockDim.x + threadIdx.x;
    int e = t >> 4;
    if (e >= E) return;
    int c4 = (t & 15) * 4;
    int s = src[e], d = dst[e];
    float norm = dis[s] * dis[d];
    float4 hv = *(const float4*)(h + (size_t)s * 64 + c4);
    float* out = acc + (size_t)d * 64 + c4;
    atomicAdd(out + 0, norm * hv.x);
    atomicAdd(out + 1, norm * hv.y);
    atomicAdd(out + 2, norm * hv.z);
    atomicAdd(out + 3, norm * hv.w);
}

// final: mu = acc64[:, :32] + bmu ; logvar = acc64[:, 32:] + blv
__global__ void k_epi(const float* __restrict__ acc, const float* __restrict__ bmu,
                      const float* __restrict__ blv, float* __restrict__ out, int n) {
    int idx = blockIdx.x * blockDim.x + threadIdx.x;
    if (idx >= n * 64) return;
    int node = idx >> 6, c = idx & 63;
    float v = acc[idx];
    if (c < 32) out[node * 32 + c] = v + bmu[c];
    else        out[(size_t)n * 32 + node * 32 + (c - 32)] = v + blv[c - 32];
}

extern "C" void kernel_launch(void* const* d_in, const int* in_sizes, int n_in,
                              void* d_out, int out_size, void* d_ws, size_t ws_size,
                              hipStream_t stream) {
    const float* x   = (const float*)d_in[0];
    const int*   ei  = (const int*)d_in[1];
    const float* W1  = (const float*)d_in[2];
    const float* b1  = (const float*)d_in[3];
    const float* W2  = (const float*)d_in[4];
    const float* b2  = (const float*)d_in[5];
    const float* Wmu = (const float*)d_in[6];
    const float* bmu = (const float*)d_in[7];
    const float* Wlv = (const float*)d_in[8];
    const float* blv = (const float*)d_in[9];
    float* out = (float*)d_out;

    int n = in_sizes[0] / 32;   // 100000
    int E = in_sizes[1] / 2;    // 1600000
    const int* src = ei;
    const int* dst = ei + E;

    float* ws    = (float*)d_ws;
    float* dis   = ws;                       // n
    float* acc32 = ws + n;                   // n*32  (n*4 bytes is 16B-aligned for n%4==0)
    float* acc64 = acc32 + (size_t)n * 32;   // n*64
    float* h     = out;                      // reuse d_out (n*64 floats) as h buffer

    hipMemsetAsync(dis, 0, (size_t)n * sizeof(float), stream);
    k_deg<<<(E + TB - 1) / TB, TB, 0, stream>>>(dst, E, dis);
    k_dis<<<(n + TB - 1) / TB, TB, 0, stream>>>(dis, n);

    // layer 1: h1 = x@W1 ; acc32 = selfloop + scatter
    k_gemm32<<<(n + 7) / 8, 256, 0, stream>>>(x, W1, nullptr, dis, h, acc32, n);
    k_scatter32<<<(E * 8 + TB - 1) / TB, TB, 0, stream>>>(src, dst, dis, h, acc32, E);

    // layer 2: input = relu(acc32 + b1). gemm reads/writes disjoint per-block node
    // ranges of acc32 (reads before barrier, writes after), so in-place is safe.
    k_gemm32<<<(n + 7) / 8, 256, 0, stream>>>(acc32, W2, b1, dis, h, acc32, n);
    k_scatter32<<<(E * 8 + TB - 1) / TB, TB, 0, stream>>>(src, dst, dis, h, acc32, E);

    // layers mu+logvar fused (64 ch): input = relu(acc32 + b2) -> acc64
    k_gemm64<<<(n + 3) / 4, 256, 0, stream>>>(acc32, Wmu, Wlv, b2, dis, h, acc64, n);
    k_scatter64<<<((size_t)E * 16 + TB - 1) / TB, TB, 0, stream>>>(src, dst, dis, h, acc64, E);

    k_epi<<<((size_t)n * 64 + TB - 1) / TB, TB, 0, stream>>>(acc64, bmu, blv, out, n);
}

// Round 2
// 471.173 us; speedup vs baseline: 6.0114x; 6.0114x over previous
//
#include <hip/hip_runtime.h>

// ---------------------------------------------------------------------------
// VGAE encoder, atomic-free aggregation:
//   counting-sort edges by dst -> per-layer [gemm -> segment-sum gather] x3
//   (mu/logvar fused to 64ch; self-loop in acc init; final bias in agg64)
// ---------------------------------------------------------------------------

#define TB 256

// ---- edge preprocessing ----------------------------------------------------

__global__ void k_hist(const int* __restrict__ dst, int E, int* __restrict__ cnt) {
    int e = blockIdx.x * blockDim.x + threadIdx.x;
    if (e < E) atomicAdd(&cnt[dst[e]], 1);
}

__global__ void k_dis(const int* __restrict__ cnt, float* __restrict__ dis, int n) {
    int i = blockIdx.x * blockDim.x + threadIdx.x;
    if (i < n) dis[i] = rsqrtf((float)cnt[i] + 1.0f);   // +1 = self loop
}

__global__ void k_blocksum(const int* __restrict__ cnt, int n, int* __restrict__ bsum) {
    __shared__ int s[256];
    int t = threadIdx.x, i = blockIdx.x * 256 + t;
    s[t] = (i < n) ? cnt[i] : 0;
    __syncthreads();
    for (int o = 128; o > 0; o >>= 1) {
        if (t < o) s[t] += s[t + o];
        __syncthreads();
    }
    if (t == 0) bsum[blockIdx.x] = s[0];
}

// single block, 1024 threads: exclusive scan of block sums (nb <= 1024)
__global__ void k_scanbsum(int* __restrict__ bsum, int nb) {
    __shared__ int s[1024];
    int t = threadIdx.x;
    int v = (t < nb) ? bsum[t] : 0;
    s[t] = v;
    __syncthreads();
    for (int o = 1; o < 1024; o <<= 1) {
        int x = (t >= o) ? s[t - o] : 0;
        __syncthreads();
        s[t] += x;
        __syncthreads();
    }
    if (t < nb) bsum[t] = s[t] - v;   // exclusive
}

// starts[i] = bsum[blk] + exclusive_within_block ; starts[n] = E
__global__ void k_scanfinal(const int* __restrict__ cnt, const int* __restrict__ bsum,
                            int n, int* __restrict__ starts) {
    __shared__ int s[256];
    int t = threadIdx.x, i = blockIdx.x * 256 + t;
    int v = (i < n) ? cnt[i] : 0;
    s[t] = v;
    __syncthreads();
    for (int o = 1; o < 256; o <<= 1) {
        int x = (t >= o) ? s[t - o] : 0;
        __syncthreads();
        s[t] += x;
        __syncthreads();
    }
    int base = bsum[blockIdx.x];
    if (i < n) starts[i] = base + s[t] - v;
    if (i == n - 1) starts[n] = base + s[t];
}

// bucket-scatter edges into dst-sorted order: es_en[pos] = {src, norm}
__global__ void k_sort(const int* __restrict__ src, const int* __restrict__ dst,
                       const int* __restrict__ starts, int* __restrict__ cursor,
                       const float* __restrict__ dis, int2* __restrict__ es_en, int E) {
    int e = blockIdx.x * blockDim.x + threadIdx.x;
    if (e >= E) return;
    int s = src[e], d = dst[e];
    int pos = starts[d] + atomicAdd(&cursor[d], 1);
    float w = dis[s] * dis[d];
    es_en[pos] = make_int2(s, __float_as_int(w));
}

// ---- per-layer kernels -----------------------------------------------------

// h = pre(in) @ W ; pre(v) = bin ? relu(v + bin[c]) : v
// block: 256 threads = 8 nodes x 32 channels
__global__ void k_gemm32(const float* __restrict__ in, const float* __restrict__ W,
                         const float* __restrict__ bin, float* __restrict__ h, int n) {
    __shared__ float Ws[32][32];
    __shared__ float Xs[8][33];
    int t = threadIdx.x;
    for (int i = t; i < 1024; i += 256) Ws[i >> 5][i & 31] = W[i];
    int r = t >> 5, c = t & 31;
    int node = blockIdx.x * 8 + r;
    {
        float v = 0.f;
        if (node < n) {
            v = in[node * 32 + c];
            if (bin) v = fmaxf(v + bin[c], 0.f);
        }
        Xs[r][c] = v;
    }
    __syncthreads();
    if (node >= n) return;
    float sum = 0.f;
#pragma unroll
    for (int k = 0; k < 32; ++k) sum += Xs[r][k] * Ws[k][c];
    h[node * 32 + c] = sum;
}

// fused mu/logvar GEMM: h64 = relu(in + bin) @ [Wmu | Wlv]
// block: 256 threads = 4 nodes x 64 channels
__global__ void k_gemm64(const float* __restrict__ in, const float* __restrict__ Wmu,
                         const float* __restrict__ Wlv, const float* __restrict__ bin,
                         float* __restrict__ h, int n) {
    __shared__ float Ws[32][64];
    __shared__ float Xs[4][33];
    int t = threadIdx.x;
    for (int i = t; i < 1024; i += 256) {
        int k = i >> 5, c = i & 31;
        Ws[k][c]      = Wmu[i];
        Ws[k][c + 32] = Wlv[i];
    }
    if (t < 128) {
        int r = t >> 5, c = t & 31;
        int node = blockIdx.x * 4 + r;
        float v = 0.f;
        if (node < n) v = fmaxf(in[node * 32 + c] + bin[c], 0.f);
        Xs[r][c] = v;
    }
    __syncthreads();
    int r = t >> 6, c = t & 63;
    int node = blockIdx.x * 4 + r;
    if (node >= n) return;
    float sum = 0.f;
#pragma unroll
    for (int k = 0; k < 32; ++k) sum += Xs[r][k] * Ws[k][c];
    h[node * 64 + c] = sum;
}

// segment-sum, 32 channels: 8 threads/node (float4 each), no atomics
__global__ void k_agg32(const int* __restrict__ starts, const int2* __restrict__ es_en,
                        const float* __restrict__ dis, const float* __restrict__ h,
                        float* __restrict__ out, int n) {
    int t = threadIdx.x;
    int node = blockIdx.x * 32 + (t >> 3);
    if (node >= n) return;
    int lane = t & 7;
    const float4* h4 = (const float4*)h;
    float dd = dis[node];
    float4 a = h4[node * 8 + lane];
    float s2 = dd * dd;
    a.x *= s2; a.y *= s2; a.z *= s2; a.w *= s2;
    int beg = starts[node], end = starts[node + 1];
    for (int j = beg; j < end; ++j) {
        int2 p = es_en[j];
        float w = __int_as_float(p.y);
        float4 hv = h4[p.x * 8 + lane];
        a.x += w * hv.x; a.y += w * hv.y; a.z += w * hv.z; a.w += w * hv.w;
    }
    ((float4*)out)[node * 8 + lane] = a;
}

// segment-sum, 64 channels + final bias + split mu/logvar output
__global__ void k_agg64(const int* __restrict__ starts, const int2* __restrict__ es_en,
                        const float* __restrict__ dis, const float* __restrict__ h,
                        const float* __restrict__ bmu, const float* __restrict__ blv,
                        float* __restrict__ out, int n) {
    int t = threadIdx.x;
    int node = blockIdx.x * 16 + (t >> 4);
    if (node >= n) return;
    int lane = t & 15;                    // float4 index into 64ch row
    const float4* h4 = (const float4*)h;
    float dd = dis[node];
    float4 a = h4[node * 16 + lane];
    float s2 = dd * dd;
    a.x *= s2; a.y *= s2; a.z *= s2; a.w *= s2;
    int beg = starts[node], end = starts[node + 1];
    for (int j = beg; j < end; ++j) {
        int2 p = es_en[j];
        float w = __int_as_float(p.y);
        float4 hv = h4[p.x * 16 + lane];
        a.x += w * hv.x; a.y += w * hv.y; a.z += w * hv.z; a.w += w * hv.w;
    }
    int c4 = lane * 4;
    float4 b;
    float* dstp;
    if (c4 < 32) {
        b = ((const float4*)bmu)[lane];
        dstp = out + (size_t)node * 32 + c4;
    } else {
        b = ((const float4*)blv)[lane - 8];
        dstp = out + (size_t)n * 32 + (size_t)node * 32 + (c4 - 32);
    }
    a.x += b.x; a.y += b.y; a.z += b.z; a.w += b.w;
    *(float4*)dstp = a;
}

// ---- launch ----------------------------------------------------------------

extern "C" void kernel_launch(void* const* d_in, const int* in_sizes, int n_in,
                              void* d_out, int out_size, void* d_ws, size_t ws_size,
                              hipStream_t stream) {
    const float* x   = (const float*)d_in[0];
    const int*   ei  = (const int*)d_in[1];
    const float* W1  = (const float*)d_in[2];
    const float* b1  = (const float*)d_in[3];
    const float* W2  = (const float*)d_in[4];
    const float* b2  = (const float*)d_in[5];
    const float* Wmu = (const float*)d_in[6];
    const float* bmu = (const float*)d_in[7];
    const float* Wlv = (const float*)d_in[8];
    const float* blv = (const float*)d_in[9];
    float* out = (float*)d_out;

    int n = in_sizes[0] / 32;   // 100000
    int E = in_sizes[1] / 2;    // 1600000
    const int* src = ei;
    const int* dst = ei + E;
    int nb = (n + 255) / 256;   // <= 1024 required by k_scanbsum

    // workspace layout (element offsets kept 4-aligned)
    int*   cnt    = (int*)d_ws;                       // n
    int*   starts = cnt + n;                          // n+4 (padded)
    int*   cursor = starts + n + 4;                   // n
    int*   bsum   = cursor + n;                       // 1024
    float* dis    = (float*)(bsum + 1024);            // n
    int2*  es_en  = (int2*)(dis + n);                 // E
    float* acc32  = (float*)(es_en + E);              // n*32
    float* h64    = acc32 + (size_t)n * 32;           // n*64
    float* h      = out;                              // layers 1-2 h buffer (n*32 of n*64)

    // ---- edge sort by dst ----
    hipMemsetAsync(cnt, 0, (size_t)n * sizeof(int), stream);
    hipMemsetAsync(cursor, 0, (size_t)n * sizeof(int), stream);
    k_hist<<<(E + TB - 1) / TB, TB, 0, stream>>>(dst, E, cnt);
    k_dis<<<(n + TB - 1) / TB, TB, 0, stream>>>(cnt, dis, n);
    k_blocksum<<<nb, 256, 0, stream>>>(cnt, n, bsum);
    k_scanbsum<<<1, 1024, 0, stream>>>(bsum, nb);
    k_scanfinal<<<nb, 256, 0, stream>>>(cnt, bsum, n, starts);
    k_sort<<<(E + TB - 1) / TB, TB, 0, stream>>>(src, dst, starts, cursor, dis, es_en, E);

    // ---- layer 1 ----
    k_gemm32<<<(n + 7) / 8, 256, 0, stream>>>(x, W1, nullptr, h, n);
    k_agg32<<<(n + 31) / 32, 256, 0, stream>>>(starts, es_en, dis, h, acc32, n);

    // ---- layer 2 ----
    k_gemm32<<<(n + 7) / 8, 256, 0, stream>>>(acc32, W2, b1, h, n);
    k_agg32<<<(n + 31) / 32, 256, 0, stream>>>(starts, es_en, dis, h, acc32, n);

    // ---- mu / logvar fused (64 ch) ----
    k_gemm64<<<(n + 3) / 4, 256, 0, stream>>>(acc32, Wmu, Wlv, b2, h64, n);
    k_agg64<<<(n + 15) / 16, 256, 0, stream>>>(starts, es_en, dis, h64, bmu, blv, out, n);
}

// Round 3
// 451.896 us; speedup vs baseline: 6.2678x; 1.0427x over previous
//
#include <hip/hip_runtime.h>

// ---------------------------------------------------------------------------
// VGAE encoder, gather-form with commuted GEMMs:
//   Agg(h @ W) == Agg(h) @ W  (Agg is linear row-mixing), so we aggregate the
//   32-channel activations FIRST, then apply the dense layer. All 3 edge
//   passes gather 128 B rows; the 256 B (64-ch) gather is eliminated.
//   counting-sort by dst once -> 3x [agg32 -> gemm epilogue]
// ---------------------------------------------------------------------------

#define TB 256

// ---- edge preprocessing ----------------------------------------------------

__global__ void k_hist(const int* __restrict__ dst, int E, int* __restrict__ cnt) {
    int e = blockIdx.x * blockDim.x + threadIdx.x;
    if (e < E) atomicAdd(&cnt[dst[e]], 1);
}

__global__ void k_dis(const int* __restrict__ cnt, float* __restrict__ dis, int n) {
    int i = blockIdx.x * blockDim.x + threadIdx.x;
    if (i < n) dis[i] = rsqrtf((float)cnt[i] + 1.0f);   // +1 = self loop
}

__global__ void k_blocksum(const int* __restrict__ cnt, int n, int* __restrict__ bsum) {
    __shared__ int s[256];
    int t = threadIdx.x, i = blockIdx.x * 256 + t;
    s[t] = (i < n) ? cnt[i] : 0;
    __syncthreads();
    for (int o = 128; o > 0; o >>= 1) {
        if (t < o) s[t] += s[t + o];
        __syncthreads();
    }
    if (t == 0) bsum[blockIdx.x] = s[0];
}

// single block, 1024 threads: exclusive scan of block sums (nb <= 1024)
__global__ void k_scanbsum(int* __restrict__ bsum, int nb) {
    __shared__ int s[1024];
    int t = threadIdx.x;
    int v = (t < nb) ? bsum[t] : 0;
    s[t] = v;
    __syncthreads();
    for (int o = 1; o < 1024; o <<= 1) {
        int x = (t >= o) ? s[t - o] : 0;
        __syncthreads();
        s[t] += x;
        __syncthreads();
    }
    if (t < nb) bsum[t] = s[t] - v;   // exclusive
}

// starts[i] = bsum[blk] + exclusive_within_block ; starts[n] = E
__global__ void k_scanfinal(const int* __restrict__ cnt, const int* __restrict__ bsum,
                            int n, int* __restrict__ starts) {
    __shared__ int s[256];
    int t = threadIdx.x, i = blockIdx.x * 256 + t;
    int v = (i < n) ? cnt[i] : 0;
    s[t] = v;
    __syncthreads();
    for (int o = 1; o < 256; o <<= 1) {
        int x = (t >= o) ? s[t - o] : 0;
        __syncthreads();
        s[t] += x;
        __syncthreads();
    }
    int base = bsum[blockIdx.x];
    if (i < n) starts[i] = base + s[t] - v;
    if (i == n - 1) starts[n] = base + s[t];
}

// bucket-scatter edges into dst-sorted order: es_en[pos] = {src, norm}
__global__ void k_sort(const int* __restrict__ src, const int* __restrict__ dst,
                       const int* __restrict__ starts, int* __restrict__ cursor,
                       const float* __restrict__ dis, int2* __restrict__ es_en, int E) {
    int e = blockIdx.x * blockDim.x + threadIdx.x;
    if (e >= E) return;
    int s = src[e], d = dst[e];
    int pos = starts[d] + atomicAdd(&cursor[d], 1);
    float w = dis[s] * dis[d];
    es_en[pos] = make_int2(s, __float_as_int(w));
}

// ---- aggregation: out[i] = dis[i]^2 h[i] + sum_{e:dst=i} norm_e h[src_e] ----
// 8 threads/node (float4 each), segment loop unrolled x2 for MLP
__global__ void k_agg32(const int* __restrict__ starts, const int2* __restrict__ es_en,
                        const float* __restrict__ dis, const float* __restrict__ h,
                        float* __restrict__ out, int n) {
    int t = threadIdx.x;
    int node = blockIdx.x * 32 + (t >> 3);
    if (node >= n) return;
    int lane = t & 7;
    const float4* h4 = (const float4*)h;
    float dd = dis[node];
    float4 a = h4[node * 8 + lane];
    float s2 = dd * dd;
    a.x *= s2; a.y *= s2; a.z *= s2; a.w *= s2;
    int j = starts[node], end = starts[node + 1];
    for (; j + 1 < end; j += 2) {
        int2 p0 = es_en[j];
        int2 p1 = es_en[j + 1];
        float w0 = __int_as_float(p0.y), w1 = __int_as_float(p1.y);
        float4 v0 = h4[p0.x * 8 + lane];
        float4 v1 = h4[p1.x * 8 + lane];
        a.x += w0 * v0.x; a.y += w0 * v0.y; a.z += w0 * v0.z; a.w += w0 * v0.w;
        a.x += w1 * v1.x; a.y += w1 * v1.y; a.z += w1 * v1.z; a.w += w1 * v1.w;
    }
    if (j < end) {
        int2 p = es_en[j];
        float w = __int_as_float(p.y);
        float4 v = h4[p.x * 8 + lane];
        a.x += w * v.x; a.y += w * v.y; a.z += w * v.z; a.w += w * v.w;
    }
    ((float4*)out)[node * 8 + lane] = a;
}

// ---- dense layers (post-aggregation epilogues) ------------------------------

// h = relu(in @ W + b) ; block: 256 threads = 8 nodes x 32 channels
__global__ void k_gemm32(const float* __restrict__ in, const float* __restrict__ W,
                         const float* __restrict__ b, float* __restrict__ h, int n) {
    __shared__ float Ws[32][32];
    __shared__ float Xs[8][33];
    int t = threadIdx.x;
    for (int i = t; i < 1024; i += 256) Ws[i >> 5][i & 31] = W[i];
    int r = t >> 5, c = t & 31;
    int node = blockIdx.x * 8 + r;
    Xs[r][c] = (node < n) ? in[node * 32 + c] : 0.f;
    __syncthreads();
    if (node >= n) return;
    float sum = b[c];
#pragma unroll
    for (int k = 0; k < 32; ++k) sum += Xs[r][k] * Ws[k][c];
    h[node * 32 + c] = fmaxf(sum, 0.f);
}

// mu = in@Wmu + bmu -> out[0:n*32] ; lv = in@Wlv + blv -> out[n*32:]
// block: 256 threads = 4 nodes x 64 channels
__global__ void k_gemm64(const float* __restrict__ in, const float* __restrict__ Wmu,
                         const float* __restrict__ Wlv, const float* __restrict__ bmu,
                         const float* __restrict__ blv, float* __restrict__ out, int n) {
    __shared__ float Ws[32][64];
    __shared__ float Xs[4][33];
    int t = threadIdx.x;
    for (int i = t; i < 1024; i += 256) {
        int k = i >> 5, c = i & 31;
        Ws[k][c]      = Wmu[i];
        Ws[k][c + 32] = Wlv[i];
    }
    if (t < 128) {
        int r = t >> 5, c = t & 31;
        int node = blockIdx.x * 4 + r;
        Xs[r][c] = (node < n) ? in[node * 32 + c] : 0.f;
    }
    __syncthreads();
    int r = t >> 6, c = t & 63;
    int node = blockIdx.x * 4 + r;
    if (node >= n) return;
    float sum = (c < 32) ? bmu[c] : blv[c - 32];
#pragma unroll
    for (int k = 0; k < 32; ++k) sum += Xs[r][k] * Ws[k][c];
    if (c < 32) out[(size_t)node * 32 + c] = sum;
    else        out[(size_t)n * 32 + (size_t)node * 32 + (c - 32)] = sum;
}

// ---- launch ----------------------------------------------------------------

extern "C" void kernel_launch(void* const* d_in, const int* in_sizes, int n_in,
                              void* d_out, int out_size, void* d_ws, size_t ws_size,
                              hipStream_t stream) {
    const float* x   = (const float*)d_in[0];
    const int*   ei  = (const int*)d_in[1];
    const float* W1  = (const float*)d_in[2];
    const float* b1  = (const float*)d_in[3];
    const float* W2  = (const float*)d_in[4];
    const float* b2  = (const float*)d_in[5];
    const float* Wmu = (const float*)d_in[6];
    const float* bmu = (const float*)d_in[7];
    const float* Wlv = (const float*)d_in[8];
    const float* blv = (const float*)d_in[9];
    float* out = (float*)d_out;

    int n = in_sizes[0] / 32;   // 100000
    int E = in_sizes[1] / 2;    // 1600000
    const int* src = ei;
    const int* dst = ei + E;
    int nb = (n + 255) / 256;   // <= 1024 required by k_scanbsum

    // workspace layout
    int*   cnt    = (int*)d_ws;                       // n
    int*   starts = cnt + n;                          // n+4 (padded)
    int*   cursor = starts + n + 4;                   // n
    int*   bsum   = cursor + n;                       // 1024
    float* dis    = (float*)(bsum + 1024);            // n
    int2*  es_en  = (int2*)(dis + n);                 // E
    float* a32    = (float*)(es_en + E);              // n*32  (aggregated)
    float* h32    = a32 + (size_t)n * 32;             // n*32  (post-gemm activations)

    // ---- edge sort by dst ----
    hipMemsetAsync(cnt, 0, (size_t)n * sizeof(int), stream);
    hipMemsetAsync(cursor, 0, (size_t)n * sizeof(int), stream);
    k_hist<<<(E + TB - 1) / TB, TB, 0, stream>>>(dst, E, cnt);
    k_dis<<<(n + TB - 1) / TB, TB, 0, stream>>>(cnt, dis, n);
    k_blocksum<<<nb, 256, 0, stream>>>(cnt, n, bsum);
    k_scanbsum<<<1, 1024, 0, stream>>>(bsum, nb);
    k_scanfinal<<<nb, 256, 0, stream>>>(cnt, bsum, n, starts);
    k_sort<<<(E + TB - 1) / TB, TB, 0, stream>>>(src, dst, starts, cursor, dis, es_en, E);

    // ---- layer 1: a1 = Agg(x); h1 = relu(a1@W1 + b1) ----
    k_agg32<<<(n + 31) / 32, 256, 0, stream>>>(starts, es_en, dis, x, a32, n);
    k_gemm32<<<(n + 7) / 8, 256, 0, stream>>>(a32, W1, b1, h32, n);

    // ---- layer 2: a2 = Agg(h1); h2 = relu(a2@W2 + b2) ----
    k_agg32<<<(n + 31) / 32, 256, 0, stream>>>(starts, es_en, dis, h32, a32, n);
    k_gemm32<<<(n + 7) / 8, 256, 0, stream>>>(a32, W2, b2, h32, n);

    // ---- mu/logvar: a3 = Agg(h2); out = a3@[Wmu|Wlv] + bias ----
    k_agg32<<<(n + 31) / 32, 256, 0, stream>>>(starts, es_en, dis, h32, a32, n);
    k_gemm64<<<(n + 3) / 4, 256, 0, stream>>>(a32, Wmu, Wlv, bmu, blv, out, n);
}

// Round 4
// 365.943 us; speedup vs baseline: 7.7400x; 1.2349x over previous
//
#include <hip/hip_runtime.h>

// ---------------------------------------------------------------------------
// VGAE encoder, gather-form, weight-factorized, bucketed counting sort.
//   Agg(h@W) == Agg(h)@W  and  norm_e*h[src] = dis_dst * (dis_src*h[src]),
//   so per layer:  a[i] = dis_i * ( g[i] + sum_{e:dst=i} g[src_e] ),
//   with g = dis (.) h computed in the previous GEMM's epilogue.
//   Edge preprocessing: 2-pass bucketed counting sort by dst, producing a
//   src-only sorted edge array + starts[] + dis[] with no global atomics in
//   the per-dst phase and L2-local writes.
// ---------------------------------------------------------------------------

#define BK_BITS 9
#define BK      (1 << BK_BITS)     // 512 dst nodes per bucket
#define BMASK   (BK - 1)
#define EPT     16                 // edges per thread in bucketing kernels
#define CHUNK   (256 * EPT)        // 4096 edges per block

// ---- pass 0: count edges per coarse bucket ---------------------------------
__global__ void k_bcnt(const int* __restrict__ dst, int E, int* __restrict__ bcnt) {
    __shared__ int lcnt[256];
    int t = threadIdx.x;
    lcnt[t] = 0;
    __syncthreads();
    int e0 = blockIdx.x * CHUNK;
#pragma unroll
    for (int i = 0; i < EPT; ++i) {
        int e = e0 + i * 256 + t;
        if (e < E) atomicAdd(&lcnt[dst[e] >> BK_BITS], 1);
    }
    __syncthreads();
    if (lcnt[t]) atomicAdd(&bcnt[t], lcnt[t]);
}

// ---- pass 0.5: exclusive scan of bucket counts (single block) --------------
__global__ void k_bscan(const int* __restrict__ bcnt, int* __restrict__ bbase,
                        int* __restrict__ bcur, int nbuck) {
    __shared__ int s[256];
    int t = threadIdx.x;
    int v = (t < nbuck) ? bcnt[t] : 0;
    s[t] = v;
    __syncthreads();
    for (int o = 1; o < 256; o <<= 1) {
        int x = (t >= o) ? s[t - o] : 0;
        __syncthreads();
        s[t] += x;
        __syncthreads();
    }
    bbase[t] = s[t] - v;
    bcur[t]  = s[t] - v;
}

// ---- pass A: scatter edges into dst-buckets (block-grouped writes) ---------
// ebuf[pos] = (src << BK_BITS) | (dst & BMASK), bucket implied by position.
__global__ void k_bucket(const int* __restrict__ src, const int* __restrict__ dst,
                         int* __restrict__ bcur, int* __restrict__ ebuf, int E) {
    __shared__ int lcnt[256];
    __shared__ int lbase[256];
    int t = threadIdx.x;
    lcnt[t] = 0;
    __syncthreads();
    int e0 = blockIdx.x * CHUNK;
    int pk[EPT];
#pragma unroll
    for (int i = 0; i < EPT; ++i) {
        int e = e0 + i * 256 + t;
        pk[i] = -1;
        if (e < E) {
            int d = dst[e];
            int b = d >> BK_BITS;
            int off = atomicAdd(&lcnt[b], 1);           // off < CHUNK = 4096
            pk[i] = (b << 21) | (off << BK_BITS) | (d & BMASK);
        }
    }
    __syncthreads();
    lbase[t] = atomicAdd(&bcur[t], lcnt[t]);
    __syncthreads();
#pragma unroll
    for (int i = 0; i < EPT; ++i) {
        int e = e0 + i * 256 + t;
        if (e < E) {
            int b   = pk[i] >> 21;
            int off = (pk[i] >> BK_BITS) & 4095;
            int dl  = pk[i] & BMASK;
            ebuf[lbase[b] + off] = (src[e] << BK_BITS) | dl;
        }
    }
}

// ---- pass B: per-bucket finalize: starts, dis, sorted src array ------------
// one 512-thread block per bucket; per-dst hist/scan/cursor all in LDS.
__global__ void k_finalize(const int* __restrict__ bbase, const int* __restrict__ bcnt,
                           int* __restrict__ starts, float* __restrict__ dis,
                           const int* __restrict__ ebuf, int* __restrict__ es,
                           int n, int E) {
    __shared__ int hist[BK];
    __shared__ int sc[BK];
    int b = blockIdx.x, t = threadIdx.x;
    int beg = bbase[b], cnt = bcnt[b], end = beg + cnt;
    hist[t] = 0;
    __syncthreads();
    for (int j = beg + t; j < end; j += BK)
        atomicAdd(&hist[ebuf[j] & BMASK], 1);
    __syncthreads();
    int cv = hist[t];
    sc[t] = cv;
    __syncthreads();
    for (int o = 1; o < BK; o <<= 1) {
        int x = (t >= o) ? sc[t - o] : 0;
        __syncthreads();
        sc[t] += x;
        __syncthreads();
    }
    int excl = sc[t] - cv;
    int g = (b << BK_BITS) + t;
    if (g < n) {
        starts[g] = beg + excl;
        dis[g] = rsqrtf((float)cv + 1.0f);   // +1 = self loop
    }
    if (b == 0 && t == 0) starts[n] = E;
    hist[t] = excl;                          // reuse as cursor
    __syncthreads();
    for (int j = beg + t; j < end; j += BK) {
        int v = ebuf[j];
        int off = atomicAdd(&hist[v & BMASK], 1);
        es[beg + off] = v >> BK_BITS;
    }
}

// ---- g0 = dis (.) x ---------------------------------------------------------
__global__ void k_scale(const float* __restrict__ x, const float* __restrict__ dis,
                        float* __restrict__ g, int n8) {
    int i = blockIdx.x * blockDim.x + threadIdx.x;
    if (i < n8) ((float4*)g)[i] = make_float4(0, 0, 0, 0);  // placeholder overwritten below
    if (i < n8) {
        float d = dis[i >> 3];
        float4 v = ((const float4*)x)[i];
        v.x *= d; v.y *= d; v.z *= d; v.w *= d;
        ((float4*)g)[i] = v;
    }
}

// ---- aggregation: a[i] = dis_i * ( g[i] + sum g[src_e] ) -------------------
// 8 threads/node (float4 each), unrolled x4
__global__ void k_agg32(const int* __restrict__ starts, const int* __restrict__ es,
                        const float* __restrict__ dis, const float* __restrict__ g,
                        float* __restrict__ out, int n) {
    int t = threadIdx.x;
    int node = blockIdx.x * 32 + (t >> 3);
    if (node >= n) return;
    int lane = t & 7;
    const float4* g4 = (const float4*)g;
    float4 a = g4[node * 8 + lane];
    int j = starts[node], end = starts[node + 1];
    for (; j + 3 < end; j += 4) {
        int s0 = es[j], s1 = es[j + 1], s2 = es[j + 2], s3 = es[j + 3];
        float4 v0 = g4[s0 * 8 + lane];
        float4 v1 = g4[s1 * 8 + lane];
        float4 v2 = g4[s2 * 8 + lane];
        float4 v3 = g4[s3 * 8 + lane];
        a.x += v0.x; a.y += v0.y; a.z += v0.z; a.w += v0.w;
        a.x += v1.x; a.y += v1.y; a.z += v1.z; a.w += v1.w;
        a.x += v2.x; a.y += v2.y; a.z += v2.z; a.w += v2.w;
        a.x += v3.x; a.y += v3.y; a.z += v3.z; a.w += v3.w;
    }
    for (; j < end; ++j) {
        float4 v = g4[es[j] * 8 + lane];
        a.x += v.x; a.y += v.y; a.z += v.z; a.w += v.w;
    }
    float d = dis[node];
    a.x *= d; a.y *= d; a.z *= d; a.w *= d;
    ((float4*)out)[node * 8 + lane] = a;
}

// ---- dense layers ----------------------------------------------------------

// gout = dis (.) relu(in @ W + b) ; 256 threads = 8 nodes x 32 channels
__global__ void k_gemm32(const float* __restrict__ in, const float* __restrict__ W,
                         const float* __restrict__ b, const float* __restrict__ dis,
                         float* __restrict__ gout, int n) {
    __shared__ float Ws[32][32];
    __shared__ float Xs[8][33];
    int t = threadIdx.x;
    for (int i = t; i < 1024; i += 256) Ws[i >> 5][i & 31] = W[i];
    int r = t >> 5, c = t & 31;
    int node = blockIdx.x * 8 + r;
    Xs[r][c] = (node < n) ? in[node * 32 + c] : 0.f;
    __syncthreads();
    if (node >= n) return;
    float sum = b[c];
#pragma unroll
    for (int k = 0; k < 32; ++k) sum += Xs[r][k] * Ws[k][c];
    gout[node * 32 + c] = dis[node] * fmaxf(sum, 0.f);
}

// mu = in@Wmu + bmu -> out[0:n*32] ; lv = in@Wlv + blv -> out[n*32:]
__global__ void k_gemm64(const float* __restrict__ in, const float* __restrict__ Wmu,
                         const float* __restrict__ Wlv, const float* __restrict__ bmu,
                         const float* __restrict__ blv, float* __restrict__ out, int n) {
    __shared__ float Ws[32][64];
    __shared__ float Xs[4][33];
    int t = threadIdx.x;
    for (int i = t; i < 1024; i += 256) {
        int k = i >> 5, c = i & 31;
        Ws[k][c]      = Wmu[i];
        Ws[k][c + 32] = Wlv[i];
    }
    if (t < 128) {
        int r = t >> 5, c = t & 31;
        int node = blockIdx.x * 4 + r;
        Xs[r][c] = (node < n) ? in[node * 32 + c] : 0.f;
    }
    __syncthreads();
    int r = t >> 6, c = t & 63;
    int node = blockIdx.x * 4 + r;
    if (node >= n) return;
    float sum = (c < 32) ? bmu[c] : blv[c - 32];
#pragma unroll
    for (int k = 0; k < 32; ++k) sum += Xs[r][k] * Ws[k][c];
    if (c < 32) out[(size_t)node * 32 + c] = sum;
    else        out[(size_t)n * 32 + (size_t)node * 32 + (c - 32)] = sum;
}

// ---- launch ----------------------------------------------------------------

extern "C" void kernel_launch(void* const* d_in, const int* in_sizes, int n_in,
                              void* d_out, int out_size, void* d_ws, size_t ws_size,
                              hipStream_t stream) {
    const float* x   = (const float*)d_in[0];
    const int*   ei  = (const int*)d_in[1];
    const float* W1  = (const float*)d_in[2];
    const float* b1  = (const float*)d_in[3];
    const float* W2  = (const float*)d_in[4];
    const float* b2  = (const float*)d_in[5];
    const float* Wmu = (const float*)d_in[6];
    const float* bmu = (const float*)d_in[7];
    const float* Wlv = (const float*)d_in[8];
    const float* blv = (const float*)d_in[9];
    float* out = (float*)d_out;

    int n = in_sizes[0] / 32;   // 100000
    int E = in_sizes[1] / 2;    // 1600000
    const int* src = ei;
    const int* dst = ei + E;
    int nbuck = (n + BK - 1) >> BK_BITS;   // 196 (<=256 required)

    // workspace layout (16B-aligned segments)
    int*   bcnt   = (int*)d_ws;                    // 256
    int*   bbase  = bcnt + 256;                    // 256
    int*   bcur   = bbase + 256;                   // 256
    int*   starts = bcur + 256;                    // n+1 (pad to mult of 4)
    int    npad   = (n + 4) & ~3;
    float* dis    = (float*)(starts + npad);       // n (n mult of 4)
    int*   es     = (int*)(dis + n);               // E
    float* a32    = (float*)(es + E);              // n*32 ; ebuf aliases first E
    float* g32    = a32 + (size_t)n * 32;          // n*32
    int*   ebuf   = (int*)a32;                     // E (dead before a32 first write)

    int nblk = (E + CHUNK - 1) / CHUNK;

    // ---- edge preprocessing ----
    hipMemsetAsync(bcnt, 0, 256 * sizeof(int), stream);
    k_bcnt<<<nblk, 256, 0, stream>>>(dst, E, bcnt);
    k_bscan<<<1, 256, 0, stream>>>(bcnt, bbase, bcur, nbuck);
    k_bucket<<<nblk, 256, 0, stream>>>(src, dst, bcur, ebuf, E);
    k_finalize<<<nbuck, BK, 0, stream>>>(bbase, bcnt, starts, dis, ebuf, es, n, E);

    // ---- g0 = dis (.) x ----
    k_scale<<<(n * 8 + 255) / 256, 256, 0, stream>>>(x, dis, g32, n * 8);

    // ---- layer 1 ----
    k_agg32<<<(n + 31) / 32, 256, 0, stream>>>(starts, es, dis, g32, a32, n);
    k_gemm32<<<(n + 7) / 8, 256, 0, stream>>>(a32, W1, b1, dis, g32, n);

    // ---- layer 2 ----
    k_agg32<<<(n + 31) / 32, 256, 0, stream>>>(starts, es, dis, g32, a32, n);
    k_gemm32<<<(n + 7) / 8, 256, 0, stream>>>(a32, W2, b2, dis, g32, n);

    // ---- mu/logvar ----
    k_agg32<<<(n + 31) / 32, 256, 0, stream>>>(starts, es, dis, g32, a32, n);
    k_gemm64<<<(n + 3) / 4, 256, 0, stream>>>(a32, Wmu, Wlv, bmu, blv, out, n);
}